// Round 1
// baseline (171.334 us; speedup 1.0000x reference)
//
#include <hip/hip_runtime.h>

// Fused 3x3 neighborhood-attention:
//   refn = l2norm_c(ref); patches = l2norm_c(reflectpad3x3(nbr))
//   d_k = <refn, patch_k>; wt = softmax_k(d); out = (sum_k wt_k*patch_k) * exp(-(nbr-ref)^2)
// Shapes: [b=2, c=64, h=256, w=256] fp32.

constexpr int C = 64, H = 256, W = 256, HW = H * W;

__global__ __launch_bounds__(256) void fused_nbr_attn(const float* __restrict__ nbr,
                                                      const float* __restrict__ ref,
                                                      float* __restrict__ out) {
  const int x   = threadIdx.x;        // 0..255 = w
  const int row = blockIdx.x;         // 0..511 = b*256 + y
  const int b   = row >> 8;
  const int y   = row & 255;

  // reflect padding (jnp 'reflect': index -1 -> 1, index H -> H-2)
  const int ym = (y == 0)     ? 1     : y - 1;
  const int yp = (y == H - 1) ? H - 2 : y + 1;
  const int xm = (x == 0)     ? 1     : x - 1;
  const int xp = (x == W - 1) ? W - 2 : x + 1;

  const float* nb = nbr + (size_t)b * C * HW;
  const float* rb = ref + (size_t)b * C * HW;
  float*       ob = out + (size_t)b * C * HW;

  int off[9];
  off[0] = ym * W + xm; off[1] = ym * W + x; off[2] = ym * W + xp;
  off[3] = y  * W + xm; off[4] = y  * W + x; off[5] = y  * W + xp;
  off[6] = yp * W + xm; off[7] = yp * W + x; off[8] = yp * W + xp;
  const int ctr = y * W + x;

  // ---- Pass A: accumulate ref sumsq, per-neighbor dot & sumsq over c ----
  float sr = 0.f;
  float dot[9], ss[9];
#pragma unroll
  for (int k = 0; k < 9; ++k) { dot[k] = 0.f; ss[k] = 0.f; }

#pragma unroll 4
  for (int c = 0; c < C; ++c) {
    const float* n = nb + c * HW;
    const float  r = rb[c * HW + ctr];
    sr = fmaf(r, r, sr);
#pragma unroll
    for (int k = 0; k < 9; ++k) {
      const float v = n[off[k]];
      dot[k] = fmaf(r, v, dot[k]);
      ss[k]  = fmaf(v, v, ss[k]);
    }
  }

  // ---- normalize + softmax over the 9 neighbors ----
  const float invr = 1.0f / fmaxf(sqrtf(sr), 1e-12f);
  float d[9], invp[9];
  float m = -INFINITY;
#pragma unroll
  for (int k = 0; k < 9; ++k) {
    invp[k] = 1.0f / fmaxf(sqrtf(ss[k]), 1e-12f);
    d[k]    = dot[k] * invr * invp[k];
    m       = fmaxf(m, d[k]);
  }
  float s = 0.f;
  float coef[9];
#pragma unroll
  for (int k = 0; k < 9; ++k) {
    const float e = __expf(d[k] - m);
    coef[k] = e;
    s += e;
  }
  const float sinv = 1.0f / s;
#pragma unroll
  for (int k = 0; k < 9; ++k) coef[k] *= sinv * invp[k];  // fold patch l2norm into weight

  // ---- Pass B: aggregate + elementwise reweight, write out ----
#pragma unroll 4
  for (int c = 0; c < C; ++c) {
    const float* n = nb + c * HW;
    const float  r = rb[c * HW + ctr];
    float a  = 0.f;
    float vc = 0.f;
#pragma unroll
    for (int k = 0; k < 9; ++k) {
      const float v = n[off[k]];
      a = fmaf(coef[k], v, a);
      if (k == 4) vc = v;  // center = original nbr at this pixel
    }
    const float diff = vc - r;
    const float wd   = __expf(-(diff * diff));   // exp(ALPHA*(nbr-ref)^2), ALPHA=-1
    ob[c * HW + ctr] = a * wd;
  }
}

extern "C" void kernel_launch(void* const* d_in, const int* in_sizes, int n_in,
                              void* d_out, int out_size, void* d_ws, size_t ws_size,
                              hipStream_t stream) {
  const float* nbr = (const float*)d_in[0];
  const float* ref = (const float*)d_in[1];
  float*       out = (float*)d_out;
  const int B = 2;  // batch
  dim3 grid(B * H);   // 512 blocks: one image row each
  dim3 block(W);      // 256 threads: one pixel each
  fused_nbr_attn<<<grid, block, 0, stream>>>(nbr, ref, out);
}

// Round 2
// 47.385 us; speedup vs baseline: 3.6158x; 3.6158x over previous
//
#include <hip/hip_runtime.h>

// Fused 3x3 neighborhood-attention, single-pass register-cached version.
// Decomposition: 8 threads per pixel, each owning 8 of the 64 channels.
// Lane layout within a wave: lane = px(3 bits) | cgroup(3 bits) so the 8
// threads of one pixel are lanes {px + 8*g} -> butterfly reduce over
// __shfl_xor masks 8/16/32.
// Shapes: [b=2, c=64, h=256, w=256] fp32.

constexpr int C = 64, H = 256, W = 256, HW = H * W;
constexpr int CG = 8;   // channels per thread

__global__ __launch_bounds__(256) void fused_nbr_attn(const float* __restrict__ nbr,
                                                      const float* __restrict__ ref,
                                                      float* __restrict__ out) {
  const int tid  = threadIdx.x;
  const int lane = tid & 63;
  const int wv   = tid >> 6;        // wave in block: 0..3
  const int px   = lane & 7;        // pixel within wave: 0..7
  const int cg   = lane >> 3;       // channel group: 0..7

  const int pix = blockIdx.x * 32 + wv * 8 + px;   // 0..131071 (b*HW + y*W + x)
  const int b   = pix >> 16;
  const int p   = pix & (HW - 1);
  const int y   = p >> 8;
  const int x   = p & (W - 1);

  // reflect padding (jnp 'reflect': -1 -> 1, H -> H-2)
  const int ym = (y == 0)     ? 1     : y - 1;
  const int yp = (y == H - 1) ? H - 2 : y + 1;
  const int xm = (x == 0)     ? 1     : x - 1;
  const int xp = (x == W - 1) ? W - 2 : x + 1;

  int off[9];
  off[0] = ym * W + xm; off[1] = ym * W + x; off[2] = ym * W + xp;
  off[3] = y  * W + xm; off[4] = y  * W + x; off[5] = y  * W + xp;
  off[6] = yp * W + xm; off[7] = yp * W + x; off[8] = yp * W + xp;
  const int ctr = y * W + x;

  const float* nb = nbr + ((size_t)b * C + cg * CG) * HW;
  const float* rb = ref + ((size_t)b * C + cg * CG) * HW;
  float*       ob = out + ((size_t)b * C + cg * CG) * HW;

  // ---- load everything once into registers (80 independent loads) ----
  float v[CG][9], r[CG];
#pragma unroll
  for (int j = 0; j < CG; ++j) {
    r[j] = rb[j * HW + ctr];
#pragma unroll
    for (int k = 0; k < 9; ++k) v[j][k] = nb[j * HW + off[k]];
  }

  // ---- partial accumulations over this thread's 8 channels ----
  float sr = 0.f;
  float dot[9], ss[9];
#pragma unroll
  for (int k = 0; k < 9; ++k) { dot[k] = 0.f; ss[k] = 0.f; }
#pragma unroll
  for (int j = 0; j < CG; ++j) {
    sr = fmaf(r[j], r[j], sr);
#pragma unroll
    for (int k = 0; k < 9; ++k) {
      dot[k] = fmaf(r[j], v[j][k], dot[k]);
      ss[k]  = fmaf(v[j][k], v[j][k], ss[k]);
    }
  }

  // ---- butterfly reduce the 19 partials across the 8 lanes of this pixel ----
#pragma unroll
  for (int m = 8; m < 64; m <<= 1) {
    sr += __shfl_xor(sr, m);
#pragma unroll
    for (int k = 0; k < 9; ++k) {
      dot[k] += __shfl_xor(dot[k], m);
      ss[k]  += __shfl_xor(ss[k], m);
    }
  }

  // ---- normalize + softmax over the 9 neighbors (redundant per lane, cheap) ----
  const float invr = 1.0f / fmaxf(sqrtf(sr), 1e-12f);
  float d[9], invp[9];
  float mx = -INFINITY;
#pragma unroll
  for (int k = 0; k < 9; ++k) {
    invp[k] = 1.0f / fmaxf(sqrtf(ss[k]), 1e-12f);
    d[k]    = dot[k] * invr * invp[k];
    mx      = fmaxf(mx, d[k]);
  }
  float s = 0.f;
  float coef[9];
#pragma unroll
  for (int k = 0; k < 9; ++k) {
    const float e = __expf(d[k] - mx);
    coef[k] = e;
    s += e;
  }
  const float sinv = 1.0f / s;
#pragma unroll
  for (int k = 0; k < 9; ++k) coef[k] *= sinv * invp[k];  // fold patch l2norm in

  // ---- aggregate + elementwise reweight from registers, write out ----
#pragma unroll
  for (int j = 0; j < CG; ++j) {
    float a = 0.f;
#pragma unroll
    for (int k = 0; k < 9; ++k) a = fmaf(coef[k], v[j][k], a);
    const float diff = v[j][4] - r[j];              // center neighbor - ref
    const float wd   = __expf(-(diff * diff));      // exp(ALPHA*(nbr-ref)^2), ALPHA=-1
    ob[j * HW + ctr] = a * wd;
  }
}

extern "C" void kernel_launch(void* const* d_in, const int* in_sizes, int n_in,
                              void* d_out, int out_size, void* d_ws, size_t ws_size,
                              hipStream_t stream) {
  const float* nbr = (const float*)d_in[0];
  const float* ref = (const float*)d_in[1];
  float*       out = (float*)d_out;
  const int total_pix = 2 * HW;           // b * h * w
  dim3 grid(total_pix / 32);              // 4096 blocks: 32 pixels each
  dim3 block(256);                        // 4 waves: 8 pixels x 8 cgroups each
  fused_nbr_attn<<<grid, block, 0, stream>>>(nbr, ref, out);
}